// Round 14
// baseline (143.628 us; speedup 1.0000x reference)
//
#include <hip/hip_runtime.h>
#include <hip/hip_bf16.h>

#define B 128
#define N 1024
#define L 512
#define D 64

typedef float f32x4 __attribute__((ext_vector_type(4)));
typedef short bf16x8 __attribute__((ext_vector_type(8)));

// 8 fp32 -> 8 bf16 (RNE) via packed HW cvt
__device__ inline bf16x8 cvt8(float4 f0, float4 f1) {
    union { __hip_bfloat162 h2[4]; bf16x8 v; } u;
    u.h2[0] = __float22bfloat162_rn(make_float2(f0.x, f0.y));
    u.h2[1] = __float22bfloat162_rn(make_float2(f0.z, f0.w));
    u.h2[2] = __float22bfloat162_rn(make_float2(f1.x, f1.y));
    u.h2[3] = __float22bfloat162_rn(make_float2(f1.z, f1.w));
    return u.v;
}

// ====================== single fused sim kernel ======================
// grid = 384 blocks = (s,b) x 256 thr (4 waves). TWO dispatches total
// (this + 1-block loss) vs r9's four (fill is the harness's own): kills
// prep kernel + 2 dispatch boundaries (~10us each, the consistent
// unexplained residue in every round's budget) + the Ibf 16MB HBM
// round-trip.
// Per block, straight-line:
//  1) count ntok/nreg inline (r0-proven reduce, 6KB reads)
//  2) reg-stage the WHOLE 512-region I panel fp32->bf16 into LDS (64KB)
//     in MFMA fragment order. Unconditional (all rows are real data);
//     validity enforced at fmax by predication, so no count dependency
//     and no clamp. Staging registers are PROLOGUE-only (lifetime does
//     not overlap compute -> no r2-style spill).
//  3) loop 1-4 token chunks: afrag reload + pure-LDS region loop
//     (zero barriers after the single post-staging one; LDS read-only)
// Fragment layout (64KB = 4096 x 16B units): unit ci: k=ci>>9 (64-reg
// chunk), g=(ci>>6)&7 (=rt*2+h), ln=ci&63: region k*64+(g>>1)*16+(ln&15),
// elems (g&1)*32+(ln>>4)*8 .. +8. Read (kk,rt,h): byte kk*8192 +
// (rt*2+h)*1024 + lane*16 -> conflict-free ds_read_b128.
__global__ __launch_bounds__(256) void sim_fused(
        const float* __restrict__ T, const float* __restrict__ I,
        const float* __restrict__ tmask, const float* __restrict__ imask,
        const int* __restrict__ Iimp, const int* __restrict__ Simp,
        float* __restrict__ sims) {
    int blk = blockIdx.x;          // 0..383 = s*128 + b
    int b = blk & (B - 1);
    int s = blk >> 7;
    int Tb = b, Ib = b;
    if (s == 1) Tb = Simp[b];
    else if (s == 2) Ib = Iimp[b];

    int tid = threadIdx.x;
    int w = tid >> 6;
    int lane = tid & 63;
    int q = lane >> 4;
    int c = lane & 15;

    __shared__ unsigned short ldsI[512 * D];     // 64 KB: whole region panel
    __shared__ float red[12];                    // 0..3 ts, 4..7 is, 8..11 sum

    // ---- 1) inline mask counts (r0-proven) ----
    float ts = 0.f, is = 0.f;
    {
        const float* tm = tmask + (size_t)Tb * N;
#pragma unroll
        for (int i = 0; i < N / 256; ++i) ts += tm[tid + i * 256];
        const float* im = imask + (size_t)Ib * L;
#pragma unroll
        for (int i = 0; i < L / 256; ++i) is += im[tid + i * 256];
    }
    for (int off = 32; off; off >>= 1) {
        ts += __shfl_down(ts, off);
        is += __shfl_down(is, off);
    }
    if (lane == 0) { red[w] = ts; red[4 + w] = is; }
    __syncthreads();
    int ntok = (int)(red[0] + red[1] + red[2] + red[3] + 0.5f);
    int nreg = (int)(red[4] + red[5] + red[6] + red[7] + 0.5f);

    // ---- 2) stage whole panel: 16 x {2 float4 loads -> cvt8 -> ds_write} ----
    const float* Ipan = I + (size_t)Ib * L * D;
    {
        int cbase = (lane & 15) * 16;            // region low bits * 16? no:
        // decode per j: gg = w + j*4 (wave-uniform), region gg>>1)*16+(lane&15)
#pragma unroll 4
        for (int j = 0; j < 16; ++j) {
            int gg = w + j * 4;                  // 0..63
            int r = (gg >> 1) * 16 + (lane & 15);
            int e = (gg & 1) * 32 + (lane >> 4) * 8;
            const float4* p = (const float4*)(Ipan + (size_t)r * D + e);
            float4 f0 = p[0], f1 = p[1];
            *(bf16x8*)(ldsI + (size_t)(tid + j * 256) * 8) = cvt8(f0, f1);
        }
        (void)cbase;
    }

    int nTokC = (ntok + 255) >> 8;               // 1..4 token chunks
    int nck = (nreg + 63) >> 6;                  // 2..8 64-region chunks
    float asum = 0.f;

    for (int tc = 0; tc < nTokC; ++tc) {
        // ---- A fragments for this token chunk (rows >= ntok masked at sum) ----
        int wt0 = (tc << 8) + w * 64;
        bf16x8 afrag[4][2];
#pragma unroll
        for (int tt = 0; tt < 4; ++tt) {
            const float* trow = T + ((size_t)Tb * N + wt0 + tt * 16 + c) * D;
#pragma unroll
            for (int h = 0; h < 2; ++h) {
                const float4* p = (const float4*)(trow + h * 32 + q * 8);
                afrag[tt][h] = cvt8(p[0], p[1]);
            }
        }

        if (tc == 0) __syncthreads();            // staging visible; LDS read-only after

        float mx[4][4];
#pragma unroll
        for (int tt = 0; tt < 4; ++tt)
#pragma unroll
            for (int i = 0; i < 4; ++i) mx[tt][i] = -3.0e38f;

        // ---- pure-LDS region loop; per-tile validity predication ----
        for (int kk = 0; kk < nck; ++kk) {
            const char* cb = (const char*)ldsI + (size_t)kk * 8192 + (size_t)lane * 16;
            int kbase = kk << 6;
#pragma unroll
            for (int rt = 0; rt < 4; ++rt) {
                int rbase = kbase + rt * 16;
                if (rbase < nreg) {              // wave-uniform branch
                    bf16x8 b0 = *(const bf16x8*)(cb + (rt * 2 + 0) * 1024);
                    bf16x8 b1 = *(const bf16x8*)(cb + (rt * 2 + 1) * 1024);
                    bool valid = (rbase + 16 <= nreg) || (c < nreg - rbase);
#pragma unroll
                    for (int tt = 0; tt < 4; ++tt) {
                        f32x4 acc = {0.f, 0.f, 0.f, 0.f};
                        acc = __builtin_amdgcn_mfma_f32_16x16x32_bf16(afrag[tt][0], b0, acc, 0, 0, 0);
                        acc = __builtin_amdgcn_mfma_f32_16x16x32_bf16(afrag[tt][1], b1, acc, 0, 0, 0);
                        if (valid) {
#pragma unroll
                            for (int i = 0; i < 4; ++i) mx[tt][i] = fmaxf(mx[tt][i], acc[i]);
                        }
                    }
                }
            }
        }

        // ---- cross-lane max over 16 region-cols ----
#pragma unroll
        for (int m = 1; m < 16; m <<= 1) {
#pragma unroll
            for (int tt = 0; tt < 4; ++tt)
#pragma unroll
                for (int i = 0; i < 4; ++i)
                    mx[tt][i] = fmaxf(mx[tt][i], __shfl_xor(mx[tt][i], m));
        }

        // ---- masked token sum (C layout: row = q*4 + i), accumulate ----
        if (c == 0) {
#pragma unroll
            for (int tt = 0; tt < 4; ++tt)
#pragma unroll
                for (int i = 0; i < 4; ++i) {
                    int row = wt0 + tt * 16 + q * 4 + i;
                    if (row < ntok) asum += mx[tt][i];
                }
        }
    }

    // ---- final reduce + direct sim write ----
    for (int off = 32; off; off >>= 1) asum += __shfl_down(asum, off);
    if (lane == 0) red[8 + w] = asum;
    __syncthreads();
    if (tid == 0)
        sims[blk] = (red[8] + red[9] + red[10] + red[11]) / (float)ntok;
}

// 1 block x 384 threads: direct hinge over sims[384]
__global__ void loss_kernel_direct(const float* __restrict__ sims,
                                   float* __restrict__ out) {
    int tid = threadIdx.x;  // 0..383
    __shared__ float w6[6];
    float per = 0.f;
    if (tid < B) {
        float anc  = sims[tid];
        float simp = sims[B + tid];
        float iimp = sims[2 * B + tid];
        per = fmaxf(1.f + iimp - anc, 0.f) + fmaxf(1.f + simp - anc, 0.f);
    }
    for (int off = 32; off; off >>= 1) per += __shfl_down(per, off);
    if ((tid & 63) == 0) w6[tid >> 6] = per;
    __syncthreads();
    if (tid == 0)
        out[0] = (w6[0] + w6[1] + w6[2] + w6[3] + w6[4] + w6[5]) / (float)B;
}

extern "C" void kernel_launch(void* const* d_in, const int* in_sizes, int n_in,
                              void* d_out, int out_size, void* d_ws, size_t ws_size,
                              hipStream_t stream) {
    const float* T     = (const float*)d_in[0];
    const float* I     = (const float*)d_in[1];
    const float* tmask = (const float*)d_in[2];
    const float* imask = (const float*)d_in[3];
    const int*   Iimp  = (const int*)d_in[4];
    const int*   Simp  = (const int*)d_in[5];
    float* sims = (float*)d_ws;                  // 384 floats

    sim_fused<<<3 * B, 256, 0, stream>>>(T, I, tmask, imask, Iimp, Simp, sims);
    loss_kernel_direct<<<1, 384, 0, stream>>>(sims, (float*)d_out);
}

// Round 15
// 122.628 us; speedup vs baseline: 1.1712x; 1.1712x over previous
//
#include <hip/hip_runtime.h>
#include <hip/hip_bf16.h>

#define B 128
#define N 1024
#define L 512
#define D 64

typedef float f32x4 __attribute__((ext_vector_type(4)));
typedef short bf16x8 __attribute__((ext_vector_type(8)));

// 8 fp32 -> 8 bf16 (RNE) via packed HW cvt
__device__ inline bf16x8 cvt8(float4 f0, float4 f1) {
    union { __hip_bfloat162 h2[4]; bf16x8 v; } u;
    u.h2[0] = __float22bfloat162_rn(make_float2(f0.x, f0.y));
    u.h2[1] = __float22bfloat162_rn(make_float2(f0.z, f0.w));
    u.h2[2] = __float22bfloat162_rn(make_float2(f1.x, f1.y));
    u.h2[3] = __float22bfloat162_rn(make_float2(f1.z, f1.w));
    return u.v;
}

// async global->LDS DMA, 16B per lane; LDS dest must be linear base+lane*16
__device__ __forceinline__ void gload16(const void* g, void* l) {
    __builtin_amdgcn_global_load_lds(
        (const __attribute__((address_space(1))) void*)g,
        (__attribute__((address_space(3))) void*)l, 16, 0, 0);
}

// ============================ bf16-workspace path ============================
// Fused pre-pass: blocks [0,B): mask counts; blocks [B,B+512): I fp32->bf16.
// The bf16 conversion is what makes the whole-panel-in-LDS sim possible:
// 512 regions x 64 d x 2B = 64KB (fp32 would be 128KB > LDS).
__global__ __launch_bounds__(256) void prep_kernel(
        const float* __restrict__ tmask, const float* __restrict__ imask,
        const float* __restrict__ I,
        int* __restrict__ counts, unsigned short* __restrict__ Ibf) {
    int blk = blockIdx.x, tid = threadIdx.x;
    if (blk < B) {
        int b = blk;
        int w = tid >> 6, lane = tid & 63;
        float ts = 0.f, is = 0.f;
        const float* tm = tmask + (size_t)b * N;
#pragma unroll
        for (int i = 0; i < N / 256; ++i) ts += tm[tid + i * 256];
        const float* im = imask + (size_t)b * L;
#pragma unroll
        for (int i = 0; i < L / 256; ++i) is += im[tid + i * 256];
        for (int off = 32; off; off >>= 1) {
            ts += __shfl_down(ts, off);
            is += __shfl_down(is, off);
        }
        __shared__ float red[8];
        if (lane == 0) { red[w] = ts; red[4 + w] = is; }
        __syncthreads();
        if (tid == 0) counts[b]     = (int)(red[0] + red[1] + red[2] + red[3] + 0.5f);
        if (tid == 1) counts[B + b] = (int)(red[4] + red[5] + red[6] + red[7] + 0.5f);
    } else {
        // 512 blocks x 256 thr x 4 chunks of 8 elems = 4,194,304 elems exactly
        int t = (blk - B) * 256 + tid;                 // 0..131071
#pragma unroll
        for (int j = 0; j < 4; ++j) {
            size_t ci = (size_t)t + (size_t)j * 131072;
            const float4* p = (const float4*)(I + ci * 8);
            *(bf16x8*)(Ibf + ci * 8) = cvt8(p[0], p[1]);
        }
    }
}

// grid = 384 blocks = (s,b) x 256 thr (4 waves x 64 tokens per chunk).
// MEASURED-BEST configuration (121.6us total, round 9): ONE block per (s,b)
// stages the whole Ibf[b] panel ONCE via a single up-front DMA burst, then
// loops the 1-4 active token-chunks internally with ZERO barriers between
// them (LDS read-only after the single prologue barrier). 384 blocks <= 512
// residency slots (64KB LDS -> 2/CU): whole grid co-resident; one
// stage-drain latency exposure per (s,b); staging traffic /4 vs chunk-blocks.
// Fragment layout per region-chunk k (4096 shorts at k*4096), 16B chunk ci in
// [0,512): g=ci>>6 (=rt*2+h), ln=ci&63: region (g>>1)*16+(ln&15),
// elems (g&1)*32+(ln>>4)*8 .. +8. Conflict-free ds_read_b128 at
// base+lane*16 + (rt*2+h)*1024.
__global__ __launch_bounds__(256, 2) void sim_kernel_bf16(
        const float* __restrict__ T, const unsigned short* __restrict__ Ibf,
        const int* __restrict__ counts,
        const int* __restrict__ Iimp, const int* __restrict__ Simp,
        float* __restrict__ sims) {
    int blk = blockIdx.x;          // 0..383 = s*128 + b
    int b = blk & (B - 1);
    int s = blk >> 7;
    int Tb = b, Ib = b;
    if (s == 1) Tb = Simp[b];
    else if (s == 2) Ib = Iimp[b];

    int tid = threadIdx.x;
    int w = tid >> 6;
    int lane = tid & 63;
    int q = lane >> 4;
    int c = lane & 15;

    int ntok = counts[Tb];         // block-uniform
    int nreg = counts[B + Ib];

    __shared__ unsigned short ldsI[512 * D];     // 64 KB: whole region panel
    __shared__ float red[4];

    // ---- staging decode: 2 x 16B DMA per thread per 64-region chunk ----
    int rloc[2], eoff[2];
#pragma unroll
    for (int j = 0; j < 2; ++j) {
        int ci = tid + j * 256;
        int g = ci >> 6, ln = ci & 63;
        rloc[j] = (g >> 1) * 16 + (ln & 15);
        eoff[j] = (g & 1) * 32 + (ln >> 4) * 8;
    }
    const unsigned short* Ibase = Ibf + (size_t)Ib * L * D;
    int nchunks = (nreg + 63) >> 6;              // 2..8 (nreg >= 128)
    int nregm1 = nreg - 1;

    // ---- issue ALL staging DMA up front (<=16 in flight per lane) ----
    for (int k = 0; k < nchunks; ++k) {
        unsigned short* buf = &ldsI[k * 4096];
        int rbase = k << 6;
#pragma unroll
        for (int j = 0; j < 2; ++j) {
            int r = rbase + rloc[j];
            if (r > nregm1) r = nregm1;          // duplicate valid row: max-neutral
            gload16(Ibase + (size_t)r * D + eoff[j], buf + (size_t)(tid + j * 256) * 8);
        }
    }

    int nTokC = (ntok + 255) >> 8;               // 1..4 active token chunks
    float asum = 0.f;

    for (int tc = 0; tc < nTokC; ++tc) {
        // ---- A fragments for this token chunk (rows >= ntok masked at sum) ----
        int wt0 = (tc << 8) + w * 64;
        bf16x8 afrag[4][2];
#pragma unroll
        for (int tt = 0; tt < 4; ++tt) {
            const float* trow = T + ((size_t)Tb * N + wt0 + tt * 16 + c) * D;
#pragma unroll
            for (int h = 0; h < 2; ++h) {
                const float4* p = (const float4*)(trow + h * 32 + q * 8);
                afrag[tt][h] = cvt8(p[0], p[1]);
            }
        }

        if (tc == 0) {
            // ONE drain + ONE barrier for the whole kernel (DMA + tc0 afrag)
            asm volatile("s_waitcnt vmcnt(0)" ::: "memory");
            __builtin_amdgcn_s_barrier();
        }

        float mx[4][4];
#pragma unroll
        for (int tt = 0; tt < 4; ++tt)
#pragma unroll
            for (int i = 0; i < 4; ++i) mx[tt][i] = -3.0e38f;

        // ---- pure-LDS region loop: no barriers, no waits, 32 MFMA/chunk ----
#pragma unroll 2
        for (int k = 0; k < nchunks; ++k) {
            const char* base = (const char*)&ldsI[k * 4096] + (size_t)lane * 16;
#pragma unroll
            for (int rt = 0; rt < 4; ++rt) {
                bf16x8 b0 = *(const bf16x8*)(base + (rt * 2 + 0) * 1024);
                bf16x8 b1 = *(const bf16x8*)(base + (rt * 2 + 1) * 1024);
#pragma unroll
                for (int tt = 0; tt < 4; ++tt) {
                    f32x4 acc = {0.f, 0.f, 0.f, 0.f};
                    acc = __builtin_amdgcn_mfma_f32_16x16x32_bf16(afrag[tt][0], b0, acc, 0, 0, 0);
                    acc = __builtin_amdgcn_mfma_f32_16x16x32_bf16(afrag[tt][1], b1, acc, 0, 0, 0);
#pragma unroll
                    for (int i = 0; i < 4; ++i) mx[tt][i] = fmaxf(mx[tt][i], acc[i]);
                }
            }
        }

        // ---- cross-lane max over 16 region-cols ----
#pragma unroll
        for (int m = 1; m < 16; m <<= 1) {
#pragma unroll
            for (int tt = 0; tt < 4; ++tt)
#pragma unroll
                for (int i = 0; i < 4; ++i)
                    mx[tt][i] = fmaxf(mx[tt][i], __shfl_xor(mx[tt][i], m));
        }

        // ---- masked token sum (C layout: row = q*4 + i), accumulate ----
        if (c == 0) {
#pragma unroll
            for (int tt = 0; tt < 4; ++tt)
#pragma unroll
                for (int i = 0; i < 4; ++i) {
                    int row = wt0 + tt * 16 + q * 4 + i;
                    if (row < ntok) asum += mx[tt][i];
                }
        }
    }

    // ---- single final reduction + direct sim write ----
    for (int off = 32; off; off >>= 1) asum += __shfl_down(asum, off);
    if (lane == 0) red[w] = asum;
    __syncthreads();
    if (tid == 0)
        sims[blk] = (red[0] + red[1] + red[2] + red[3]) / (float)ntok;
}

// 1 block x 384 threads: direct hinge over sims[384]
__global__ void loss_kernel_direct(const float* __restrict__ sims,
                                   float* __restrict__ out) {
    int tid = threadIdx.x;  // 0..383
    __shared__ float w6[6];
    float per = 0.f;
    if (tid < B) {
        float anc  = sims[tid];
        float simp = sims[B + tid];
        float iimp = sims[2 * B + tid];
        per = fmaxf(1.f + iimp - anc, 0.f) + fmaxf(1.f + simp - anc, 0.f);
    }
    for (int off = 32; off; off >>= 1) per += __shfl_down(per, off);
    if ((tid & 63) == 0) w6[tid >> 6] = per;
    __syncthreads();
    if (tid == 0)
        out[0] = (w6[0] + w6[1] + w6[2] + w6[3] + w6[4] + w6[5]) / (float)B;
}

// ===================== fallback path (tiny workspace, r3) =====================
__global__ __launch_bounds__(256) void count_kernel(
        const float* __restrict__ tmask, const float* __restrict__ imask,
        int* __restrict__ counts) {
    int b = blockIdx.x, tid = threadIdx.x;
    int w = tid >> 6, lane = tid & 63;
    float ts = 0.f, is = 0.f;
    const float* tm = tmask + (size_t)b * N;
#pragma unroll
    for (int i = 0; i < N / 256; ++i) ts += tm[tid + i * 256];
    const float* im = imask + (size_t)b * L;
#pragma unroll
    for (int i = 0; i < L / 256; ++i) is += im[tid + i * 256];
    for (int off = 32; off; off >>= 1) {
        ts += __shfl_down(ts, off);
        is += __shfl_down(is, off);
    }
    __shared__ float red[8];
    if (lane == 0) { red[w] = ts; red[4 + w] = is; }
    __syncthreads();
    if (tid == 0) counts[b]     = (int)(red[0] + red[1] + red[2] + red[3] + 0.5f);
    if (tid == 1) counts[B + b] = (int)(red[4] + red[5] + red[6] + red[7] + 0.5f);
}

// verbatim round-3 sim kernel (passed): fp32 DMA staging, 3x16KB LDS
__global__ __launch_bounds__(256, 3) void sim_kernel_f32(
        const float* __restrict__ T, const float* __restrict__ I,
        const int* __restrict__ counts,
        const int* __restrict__ Iimp, const int* __restrict__ Simp,
        float* __restrict__ partials) {
    int blk = blockIdx.x;
    int chunk = blk & 3;
    int bs = blk >> 2;
    int b = bs & (B - 1);
    int s = bs >> 7;
    int Tb = b, Ib = b;
    if (s == 1) Tb = Simp[b];
    else if (s == 2) Ib = Iimp[b];

    int tid = threadIdx.x;
    int w = tid >> 6;
    int lane = tid & 63;
    int q = lane >> 4;
    int c = lane & 15;

    int ntok = counts[Tb];
    int nreg = counts[B + Ib];

    int tok0 = chunk << 8;
    if (chunk != 0 && tok0 >= ntok) {
        if (tid == 0) partials[blk] = 0.f;
        return;
    }

    __shared__ float ldsI[3][4096];
    __shared__ float red[4];

    int wt0 = tok0 + w * 64;
    bf16x8 afrag[4][2];
#pragma unroll
    for (int tt = 0; tt < 4; ++tt) {
        const float* trow = T + ((size_t)Tb * N + wt0 + tt * 16 + c) * D;
#pragma unroll
        for (int h = 0; h < 2; ++h) {
            const float4* p = (const float4*)(trow + h * 32 + q * 8);
            afrag[tt][h] = cvt8(p[0], p[1]);
        }
    }

    float mx[4][4];
#pragma unroll
    for (int tt = 0; tt < 4; ++tt)
#pragma unroll
        for (int i = 0; i < 4; ++i) mx[tt][i] = -3.0e38f;

    int rloc[4], foff[4];
#pragma unroll
    for (int j = 0; j < 4; ++j) {
        int ci = tid + j * 256;
        int fh = ci >> 7, idx = ci & 127, half = idx >> 6, ln2 = idx & 63;
        rloc[j] = (fh >> 1) * 16 + (ln2 & 15);
        foff[j] = (fh & 1) * 32 + (ln2 >> 4) * 8 + half * 4;
    }
    const float* Ibase = I + (size_t)Ib * L * D;
    int nchunks = (nreg + 63) >> 6;
    int nregm1 = nreg - 1;

    auto stage = [&](int k) {
        float* buf = &ldsI[k % 3][0];
        int rbase = k << 6;
#pragma unroll
        for (int j = 0; j < 4; ++j) {
            int r = rbase + rloc[j];
            if (r > nregm1) r = nregm1;
            gload16(Ibase + (size_t)r * D + foff[j], buf + (tid + j * 256) * 4);
        }
    };

    asm volatile("s_waitcnt vmcnt(0)" ::: "memory");
    stage(0);
    stage(1);
    asm volatile("s_waitcnt vmcnt(4)" ::: "memory");
    __builtin_amdgcn_s_barrier();

    for (int k = 0; k < nchunks; ++k) {
        if (k + 2 < nchunks) stage(k + 2);

        const char* base = (const char*)&ldsI[k % 3][0] + (size_t)lane * 16;
#pragma unroll
        for (int rt = 0; rt < 4; ++rt) {
            float4 e0 = *(const float4*)(base + (rt * 2 + 0) * 2048);
            float4 e1 = *(const float4*)(base + (rt * 2 + 0) * 2048 + 1024);
            float4 e2 = *(const float4*)(base + (rt * 2 + 1) * 2048);
            float4 e3 = *(const float4*)(base + (rt * 2 + 1) * 2048 + 1024);
            bf16x8 b0 = cvt8(e0, e1);
            bf16x8 b1 = cvt8(e2, e3);
#pragma unroll
            for (int tt = 0; tt < 4; ++tt) {
                f32x4 acc = {0.f, 0.f, 0.f, 0.f};
                acc = __builtin_amdgcn_mfma_f32_16x16x32_bf16(afrag[tt][0], b0, acc, 0, 0, 0);
                acc = __builtin_amdgcn_mfma_f32_16x16x32_bf16(afrag[tt][1], b1, acc, 0, 0, 0);
#pragma unroll
                for (int i = 0; i < 4; ++i) mx[tt][i] = fmaxf(mx[tt][i], acc[i]);
            }
        }

        if (k + 1 < nchunks) {
            if (k + 2 < nchunks)
                asm volatile("s_waitcnt vmcnt(4) lgkmcnt(0)" ::: "memory");
            else
                asm volatile("s_waitcnt vmcnt(0) lgkmcnt(0)" ::: "memory");
            __builtin_amdgcn_s_barrier();
        }
    }

#pragma unroll
    for (int m = 1; m < 16; m <<= 1) {
#pragma unroll
        for (int tt = 0; tt < 4; ++tt)
#pragma unroll
            for (int i = 0; i < 4; ++i)
                mx[tt][i] = fmaxf(mx[tt][i], __shfl_xor(mx[tt][i], m));
    }

    float bsum = 0.f;
    if (c == 0) {
#pragma unroll
        for (int tt = 0; tt < 4; ++tt)
#pragma unroll
            for (int i = 0; i < 4; ++i) {
                int row = wt0 + tt * 16 + q * 4 + i;
                if (row < ntok) bsum += mx[tt][i];
            }
    }
    for (int off = 32; off; off >>= 1) bsum += __shfl_down(bsum, off);
    if (lane == 0) red[w] = bsum;
    __syncthreads();
    if (tid == 0)
        partials[blk] = (red[0] + red[1] + red[2] + red[3]) / (float)ntok;
}

// 1 block x 384 threads: fold 1536 partials -> 384 sims -> hinge -> loss
__global__ void loss_kernel(const float* __restrict__ partials,
                            float* __restrict__ out) {
    int tid = threadIdx.x;  // 0..383
    __shared__ float simsL[384];
    __shared__ float w6[6];
    const float4* p4 = (const float4*)partials;
    float4 v = p4[tid];
    simsL[tid] = v.x + v.y + v.z + v.w;
    __syncthreads();
    float per = 0.f;
    if (tid < B) {
        float anc  = simsL[tid];
        float simp = simsL[B + tid];
        float iimp = simsL[2 * B + tid];
        per = fmaxf(1.f + iimp - anc, 0.f) + fmaxf(1.f + simp - anc, 0.f);
    }
    for (int off = 32; off; off >>= 1) per += __shfl_down(per, off);
    if ((tid & 63) == 0) w6[tid >> 6] = per;
    __syncthreads();
    if (tid == 0)
        out[0] = (w6[0] + w6[1] + w6[2] + w6[3] + w6[4] + w6[5]) / (float)B;
}

extern "C" void kernel_launch(void* const* d_in, const int* in_sizes, int n_in,
                              void* d_out, int out_size, void* d_ws, size_t ws_size,
                              hipStream_t stream) {
    const float* T     = (const float*)d_in[0];
    const float* I     = (const float*)d_in[1];
    const float* tmask = (const float*)d_in[2];
    const float* imask = (const float*)d_in[3];
    const int*   Iimp  = (const int*)d_in[4];
    const int*   Simp  = (const int*)d_in[5];
    // ws: counts[256] ints @0 | sims/partials f32 @1024 | Ibf bf16 @8192
    int*   counts   = (int*)d_ws;
    float* partials = (float*)((char*)d_ws + 1024);
    size_t need_bf16 = 8192 + (size_t)B * L * D * sizeof(unsigned short);

    if (ws_size >= need_bf16) {
        unsigned short* Ibf = (unsigned short*)((char*)d_ws + 8192);
        prep_kernel<<<B + 512, 256, 0, stream>>>(tmask, imask, I, counts, Ibf);
        sim_kernel_bf16<<<3 * B, 256, 0, stream>>>(T, Ibf, counts, Iimp, Simp, partials);
        loss_kernel_direct<<<1, 384, 0, stream>>>(partials, (float*)d_out);
    } else {
        count_kernel<<<B, 256, 0, stream>>>(tmask, imask, counts);
        sim_kernel_f32<<<3 * B * 4, 256, 0, stream>>>(T, I, counts, Iimp, Simp, partials);
        loss_kernel<<<1, 384, 0, stream>>>(partials, (float*)d_out);
    }
}